// Round 2
// baseline (344.989 us; speedup 1.0000x reference)
//
#include <hip/hip_runtime.h>
#include <stdint.h>

#define CNT 8
#define L1D 3072
#define NB 16384
#define BM 32
#define BN 128
#define KITERS 48            // K-tiles of 64

typedef float  float4v  __attribute__((ext_vector_type(4)));
typedef short  short8   __attribute__((ext_vector_type(8)));

__device__ __forceinline__ unsigned short f2bf(float f) {
  uint32_t u = __builtin_bit_cast(uint32_t, f);
  u += 0x7fffu + ((u >> 16) & 1u);   // RNE; inputs are finite
  return (unsigned short)(u >> 16);
}

// Combined weights written PRE-FRAGMENTED in MFMA B-fragment order:
//   frag(ntile n16, kstep kk, lane l) = 16B at ((n16*96 + kk)*64 + l)*8 shorts
//   lane l = sub*16 + r  holds  W[n16*16 + r][kk*32 + sub*8 .. +8]
// so a wave's B-fragment load is ONE coalesced global_load_dwordx4 (1 KB/wave),
// and B never touches LDS in the main GEMM.
__global__ void prep_kernel(const float* __restrict__ l1w, const float* __restrict__ l1b,
                            const float* __restrict__ l1fw, const float* __restrict__ l1fb,
                            unsigned short* __restrict__ cw, float* __restrict__ cb) {
  const int n = blockIdx.y;                       // 0..127  (= bucket*16 + j)
  const int k = blockIdx.x * 256 + threadIdx.x;   // 0..3071
  const unsigned short v = f2bf(l1w[n * L1D + k] + l1fw[(n & 15) * L1D + k]);
  const int kk  = k >> 5;
  const int sub = (k >> 3) & 3;
  const int e   = k & 7;
  const int lane = sub * 16 + (n & 15);
  cw[(((n >> 4) * 96 + kk) * 64 + lane) * 8 + e] = v;
  if (blockIdx.x == 0 && n == 0 && threadIdx.x < 128)
    cb[threadIdx.x] = l1b[threadIdx.x] + l1fb[threadIdx.x & 15];
}

struct __align__(16) EpSMem {
  float yg[BM][20];                 // gathered per-row y (16 used, pad 20)
  float l2w[960 * 9];               // [(n*30+k)*9 + b]
  float outw[256];                  // [n*8+b]
  float l2b[256];                   // [b*32+n]
  float bias[128];                  // combined l1 bias
  int   buck[BM];
};                                  // ~39.8 KB -> 2 blocks/CU trivially fit

// Barrier-free, LDS-free main loop: A direct global->reg->f2bf, B direct
// global->reg (pre-fragmented). Triple-buffered register prefetch (depth-2
// K-tiles) covers HBM latency; raw s_barrier every 12 iters bounds wave
// drift so the 4x intra-block A reuse stays L1-resident.
__global__ __launch_bounds__(256, 2) void fused_kernel(
    const float* __restrict__ x, const int* __restrict__ lsi,
    const unsigned short* __restrict__ cw, const float* __restrict__ cb,
    const float* __restrict__ gl2w, const float* __restrict__ gl2b,
    const float* __restrict__ goutw, const float* __restrict__ goutb,
    float* __restrict__ out) {
  __shared__ EpSMem sm;
  const int tid  = threadIdx.x;
  const int lane = tid & 63;
  const int wid  = tid >> 6;
  const int rowbase = blockIdx.x * BM;

  const int r16 = lane & 15;        // row within 16-tile
  const int kc  = lane >> 4;        // 8-elem k-chunk within 32

  // A: lane reads x[rowbase + i*16 + r16][it*64 + ks*32 + kc*8 .. +8]
  const float* aPtr0 = x + (size_t)(rowbase + 0 * 16 + r16) * L1D + kc * 8;
  const float* aPtr1 = x + (size_t)(rowbase + 1 * 16 + r16) * L1D + kc * 8;
  // B: wave wid owns n-tiles {2wid, 2wid+1}
  const unsigned short* bPtr0 = cw + (size_t)(2 * wid + 0) * (96 * 512) + lane * 8;
  const unsigned short* bPtr1 = cw + (size_t)(2 * wid + 1) * (96 * 512) + lane * 8;

  float4v acc[2][2];
#pragma unroll
  for (int i = 0; i < 2; ++i)
#pragma unroll
    for (int j = 0; j < 2; ++j) acc[i][j] = float4v{0.f, 0.f, 0.f, 0.f};

  struct Buf { float4v a[8]; short8 b[4]; };   // a[(i*2+ks)*2+h], b[j*2+ks]
  Buf b0, b1, b2;

#define LOADBUF(B_, IT_)                                                              \
  {                                                                                   \
    const int koff = (IT_) * 64;                                                      \
    _Pragma("unroll")                                                                 \
    for (int ks = 0; ks < 2; ++ks) {                                                  \
      _Pragma("unroll")                                                               \
      for (int h = 0; h < 2; ++h) {                                                   \
        (B_).a[(0 * 2 + ks) * 2 + h] = *(const float4v*)(aPtr0 + koff + ks * 32 + h * 4); \
        (B_).a[(1 * 2 + ks) * 2 + h] = *(const float4v*)(aPtr1 + koff + ks * 32 + h * 4); \
      }                                                                               \
      (B_).b[0 * 2 + ks] = *(const short8*)(bPtr0 + ((IT_) * 2 + ks) * 512);          \
      (B_).b[1 * 2 + ks] = *(const short8*)(bPtr1 + ((IT_) * 2 + ks) * 512);          \
    }                                                                                 \
  }

#define COMPUTEBUF(B_)                                                                \
  {                                                                                   \
    _Pragma("unroll")                                                                 \
    for (int ks = 0; ks < 2; ++ks) {                                                  \
      short8 afr[2];                                                                  \
      _Pragma("unroll")                                                               \
      for (int i = 0; i < 2; ++i) {                                                   \
        const float4v lo = (B_).a[(i * 2 + ks) * 2 + 0];                              \
        const float4v hi = (B_).a[(i * 2 + ks) * 2 + 1];                              \
        afr[i] = short8{(short)f2bf(lo.x), (short)f2bf(lo.y), (short)f2bf(lo.z),      \
                        (short)f2bf(lo.w), (short)f2bf(hi.x), (short)f2bf(hi.y),      \
                        (short)f2bf(hi.z), (short)f2bf(hi.w)};                        \
      }                                                                               \
      _Pragma("unroll")                                                               \
      for (int i = 0; i < 2; ++i)                                                     \
        _Pragma("unroll")                                                             \
        for (int j = 0; j < 2; ++j)                                                   \
          acc[i][j] = __builtin_amdgcn_mfma_f32_16x16x32_bf16(afr[i], (B_).b[j * 2 + ks], \
                                                              acc[i][j], 0, 0, 0);    \
    }                                                                                 \
  }

  LOADBUF(b0, 0);
  LOADBUF(b1, 1);
  LOADBUF(b2, 2);
  for (int it = 0; it < KITERS; it += 3) {
    COMPUTEBUF(b0); if (it + 3 < KITERS) LOADBUF(b0, it + 3);
    COMPUTEBUF(b1); if (it + 4 < KITERS) LOADBUF(b1, it + 4);
    COMPUTEBUF(b2); if (it + 5 < KITERS) LOADBUF(b2, it + 5);
    if (it == 12 || it == 24 || it == 36)
      __builtin_amdgcn_s_barrier();   // raw rendezvous (no vmcnt drain): bounds wave drift for L1 A-reuse
  }
#undef LOADBUF
#undef COMPUTEBUF

  // ---- epilogue: stage tables into LDS (first LDS use in the kernel) ----
  if (tid < BM)  sm.buck[tid] = lsi[rowbase + tid];
  if (tid < 128) sm.bias[tid] = cb[tid];
  {
    const int b2 = tid >> 5, n2 = tid & 31;
    sm.outw[n2 * 8 + b2] = goutw[tid];   // out_w[b][n] -> [n*8+b]
    sm.l2b[tid] = gl2b[tid];
  }
  for (int i = tid; i < 960 * 8; i += 256) {
    const int b = i / 960;
    const int rem = i - b * 960;            // = n*30+k
    sm.l2w[rem * 9 + b] = gl2w[i];
  }
  __syncthreads();

  // scatter accumulators: row r needs n-tile == bucket[r] (16-aligned gather)
#pragma unroll
  for (int i = 0; i < 2; ++i)
#pragma unroll
    for (int j = 0; j < 2; ++j) {
      const int nt = wid * 2 + j;
#pragma unroll
      for (int rg = 0; rg < 4; ++rg) {
        const int r = i * 16 + (lane >> 4) * 4 + rg;  // C/D: col=lane&15, row=quad*4+reg
        if (sm.buck[r] == nt) sm.yg[r][lane & 15] = acc[i][j][rg];
      }
    }
  __syncthreads();

  // tail network: 8 threads per row, 4 l2-neurons each, shuffle-reduce (width 8)
  {
    const int r = tid >> 3, q = tid & 7;
    const int b = sm.buck[r];
    float act[30];
#pragma unroll
    for (int c = 0; c < 15; ++c) {
      const float v = sm.yg[r][c] + sm.bias[b * 16 + c];
      act[c]      = fminf(v * v * (127.0f / 128.0f), 1.0f);   // square part (>=0, clip hi only)
      act[15 + c] = fminf(fmaxf(v, 0.0f), 1.0f);              // linear part
    }
    const float y15 = sm.yg[r][15] + sm.bias[b * 16 + 15];    // l1c_out + l1f_out
    float o = 0.0f;
#pragma unroll
    for (int nn = 0; nn < 4; ++nn) {
      const int n = q * 4 + nn;
      float s = sm.l2b[b * 32 + n];
#pragma unroll
      for (int k = 0; k < 30; ++k) s += act[k] * sm.l2w[(n * 30 + k) * 9 + b];
      s = fminf(fmaxf(s, 0.0f), 1.0f);
      o += s * sm.outw[n * 8 + b];
    }
    o += __shfl_down(o, 4, 8);
    o += __shfl_down(o, 2, 8);
    o += __shfl_down(o, 1, 8);
    if (q == 0) out[rowbase + r] = o + y15 + goutb[b];
  }
}

extern "C" void kernel_launch(void* const* d_in, const int* in_sizes, int n_in,
                              void* d_out, int out_size, void* d_ws, size_t ws_size,
                              hipStream_t stream) {
  const float* x    = (const float*)d_in[0];
  const int*   lsi  = (const int*)d_in[1];
  const float* l1w  = (const float*)d_in[2];
  const float* l1b  = (const float*)d_in[3];
  const float* l1fw = (const float*)d_in[4];
  const float* l1fb = (const float*)d_in[5];
  const float* l2w  = (const float*)d_in[6];
  const float* l2b  = (const float*)d_in[7];
  const float* outw = (const float*)d_in[8];
  const float* outb = (const float*)d_in[9];
  float* out = (float*)d_out;

  unsigned short* cw = (unsigned short*)d_ws;                    // 128*3072 bf16 = 786432 B (fragment order)
  float* cb = (float*)((char*)d_ws + 128 * L1D * sizeof(unsigned short)); // +512 B

  prep_kernel<<<dim3(12, 128), 256, 0, stream>>>(l1w, l1b, l1fw, l1fb, cw, cb);
  fused_kernel<<<NB / BM, 256, 0, stream>>>(x, lsi, cw, cb, l2w, l2b, outw, outb, out);
}

// Round 3
// 306.326 us; speedup vs baseline: 1.1262x; 1.1262x over previous
//
#include <hip/hip_runtime.h>
#include <stdint.h>

#define CNT 8
#define L1D 3072
#define NB 16384
#define BM 32
#define BN 128
#define KITERS 48            // K-tiles of 64

typedef float  float4v  __attribute__((ext_vector_type(4)));
typedef short  short8   __attribute__((ext_vector_type(8)));

__device__ __forceinline__ unsigned short f2bf(float f) {
  uint32_t u = __builtin_bit_cast(uint32_t, f);
  u += 0x7fffu + ((u >> 16) & 1u);   // RNE; inputs are finite
  return (unsigned short)(u >> 16);
}

__device__ __forceinline__ void gload_lds16(const void* g, void* l) {
  __builtin_amdgcn_global_load_lds((const __attribute__((address_space(1))) unsigned int*)g,
                                   (__attribute__((address_space(3))) unsigned int*)l, 16, 0, 0);
}

// Combined weights PRE-FRAGMENTED in MFMA B-fragment order:
//   frag(ntile, kk, lane) = 16B at ((ntile*96 + kk)*64 + lane)*8 shorts
//   lane l = sub*16 + r holds W[ntile*16 + r][kk*32 + sub*8 .. +8]
// so a wave's B-fragment stage is ONE linear gload_lds (1 KB/wave/inst).
__global__ void prep_kernel(const float* __restrict__ l1w, const float* __restrict__ l1b,
                            const float* __restrict__ l1fw, const float* __restrict__ l1fb,
                            unsigned short* __restrict__ cw, float* __restrict__ cb) {
  const int n = blockIdx.y;                       // 0..127  (= bucket*16 + j)
  const int k = blockIdx.x * 256 + threadIdx.x;   // 0..3071
  const unsigned short v = f2bf(l1w[n * L1D + k] + l1fw[(n & 15) * L1D + k]);
  const int kk  = k >> 5;
  const int sub = (k >> 3) & 3;
  const int e   = k & 7;
  const int lane = sub * 16 + (n & 15);
  cw[(((n >> 4) * 96 + kk) * 64 + lane) * 8 + e] = v;
  if (blockIdx.x == 0 && n == 0 && threadIdx.x < 128)
    cb[threadIdx.x] = l1b[threadIdx.x] + l1fb[threadIdx.x & 15];
}

union __align__(16) SMem {
  struct {
    float A[2][BM * 64];                 // 16384 B  [buf][row*64 + kf], row stride 256B, XOR-swizzled
    unsigned short Bf[2][4][4][512];     // 32768 B  [buf][wave][frag j*2+ks][lane*8+e]
  } st;                                  // 49152 B total -> 2 blocks/CU
  struct {
    float yg[BM][20];
    float l2w[960 * 9];                  // [(n*30+k)*9 + b]
    float outw[256];                     // [n*8+b]
    float l2b[256];                      // [b*32+n]
    float bias[128];
    int   buck[BM];
  } ep;                                  // 39808 B
};

// Counted-vmcnt LDS pipeline (T3+T4): ALL main-loop VMEM is global_load_lds
// (no reg dest -> compiler emits no auto-waitcnt); our asm vmcnt(6) keeps the
// next tile's 6 loads in flight across every barrier. A staged fp32 with XOR
// source-swizzle (read applies the same XOR); bf16 convert on read. B staged
// linear per-wave (pre-fragmented in L2).
__global__ __launch_bounds__(256, 2) void fused_kernel(
    const float* __restrict__ x, const int* __restrict__ lsi,
    const unsigned short* __restrict__ cw, const float* __restrict__ cb,
    const float* __restrict__ gl2w, const float* __restrict__ gl2b,
    const float* __restrict__ goutw, const float* __restrict__ goutb,
    float* __restrict__ out) {
  __shared__ SMem sm;
  const int tid  = threadIdx.x;
  const int lane = tid & 63;
  const int wid  = tid >> 6;
  const int rowbase = blockIdx.x * BM;

  float4v acc[2][2];
#pragma unroll
  for (int i = 0; i < 2; ++i)
#pragma unroll
    for (int j = 0; j < 2; ++j) acc[i][j] = float4v{0.f, 0.f, 0.f, 0.f};

  // staging geometry (all LDS bases wave-uniform; global addrs per-lane)
  const int arow_in_blk = (lane >> 4);                 // 0..3 rows per inst
  const int acol16      = (lane & 15);                 // 16B chunk within 256B row

#define STAGE(BUF_, IT_)                                                               \
  {                                                                                    \
    _Pragma("unroll")                                                                  \
    for (int q = 0; q < 2; ++q) {                                                      \
      const int row  = wid * 8 + q * 4 + arow_in_blk;                                  \
      const int cswz = ((acol16 * 16) ^ ((row & 7) << 4)) >> 2;  /* float idx */       \
      gload_lds16(x + (size_t)(rowbase + row) * L1D + (IT_) * 64 + cswz,               \
                  &sm.st.A[BUF_][(wid * 8 + q * 4) * 64]);                             \
    }                                                                                  \
    _Pragma("unroll")                                                                  \
    for (int f = 0; f < 4; ++f)                                                        \
      gload_lds16(cw + (((size_t)(wid * 2 + (f >> 1)) * 96 + (IT_) * 2 + (f & 1)) * 64 \
                        + lane) * 8,                                                   \
                  &sm.st.Bf[BUF_][wid][f][0]);                                         \
  }

#define COMPUTE(BUF_)                                                                  \
  {                                                                                    \
    short8 afr[2][2], bfr[2][2];                                                       \
    const int sw = (lane & 7) << 4;                                                    \
    _Pragma("unroll")                                                                  \
    for (int ks = 0; ks < 2; ++ks) {                                                   \
      _Pragma("unroll")                                                                \
      for (int i = 0; i < 2; ++i) {                                                    \
        const int r   = i * 16 + (lane & 15);                                          \
        const int cbb = ks * 128 + (lane >> 4) * 32;                                   \
        const float4v lo = *(const float4v*)((const char*)&sm.st.A[BUF_][0] +          \
                                             r * 256 + ((cbb) ^ sw));                  \
        const float4v hi = *(const float4v*)((const char*)&sm.st.A[BUF_][0] +          \
                                             r * 256 + ((cbb + 16) ^ sw));             \
        afr[i][ks] = short8{(short)f2bf(lo.x), (short)f2bf(lo.y), (short)f2bf(lo.z),   \
                            (short)f2bf(lo.w), (short)f2bf(hi.x), (short)f2bf(hi.y),   \
                            (short)f2bf(hi.z), (short)f2bf(hi.w)};                     \
      }                                                                                \
      _Pragma("unroll")                                                                \
      for (int j = 0; j < 2; ++j)                                                      \
        bfr[j][ks] = *(const short8*)&sm.st.Bf[BUF_][wid][j * 2 + ks][lane * 8];       \
    }                                                                                  \
    _Pragma("unroll")                                                                  \
    for (int ks = 0; ks < 2; ++ks)                                                     \
      _Pragma("unroll")                                                                \
      for (int i = 0; i < 2; ++i)                                                      \
        _Pragma("unroll")                                                              \
        for (int j = 0; j < 2; ++j)                                                    \
          acc[i][j] = __builtin_amdgcn_mfma_f32_16x16x32_bf16(afr[i][ks], bfr[j][ks],  \
                                                              acc[i][j], 0, 0, 0);     \
  }

  // prologue: tiles 0,1 in flight; wait for tile 0 only
  STAGE(0, 0)
  STAGE(1, 1)
  asm volatile("s_waitcnt vmcnt(6)" ::: "memory");
  __builtin_amdgcn_s_barrier();

#pragma unroll 1
  for (int it = 0; it < KITERS; it += 2) {
    COMPUTE(0)
    asm volatile("" ::: "memory");
    __builtin_amdgcn_s_barrier();                 // all waves done reading buf0
    if (it + 2 < KITERS) {
      STAGE(0, it + 2)
      asm volatile("s_waitcnt vmcnt(6)" ::: "memory");   // tile it+1 landed; it+2 in flight
    } else {
      asm volatile("s_waitcnt vmcnt(0)" ::: "memory");
    }
    __builtin_amdgcn_s_barrier();                 // everyone's tile it+1 landed

    COMPUTE(1)
    asm volatile("" ::: "memory");
    __builtin_amdgcn_s_barrier();                 // all waves done reading buf1
    if (it + 3 < KITERS) {
      STAGE(1, it + 3)
      asm volatile("s_waitcnt vmcnt(6)" ::: "memory");
    } else {
      asm volatile("s_waitcnt vmcnt(0)" ::: "memory");
    }
    __builtin_amdgcn_s_barrier();
  }
#undef STAGE
#undef COMPUTE

  __syncthreads();   // staging LDS dead; epilogue view begins

  // ---- epilogue: stage tables into (aliased) LDS ----
  if (tid < BM)  sm.ep.buck[tid] = lsi[rowbase + tid];
  if (tid < 128) sm.ep.bias[tid] = cb[tid];
  {
    const int b2 = tid >> 5, n2 = tid & 31;
    sm.ep.outw[n2 * 8 + b2] = goutw[tid];   // out_w[b][n] -> [n*8+b]
    sm.ep.l2b[tid] = gl2b[tid];
  }
  for (int i = tid; i < 960 * 8; i += 256) {
    const int b = i / 960;
    const int rem = i - b * 960;            // = n*30+k
    sm.ep.l2w[rem * 9 + b] = gl2w[i];
  }
  __syncthreads();

  // scatter accumulators: row r needs n-tile == bucket[r] (16-aligned gather)
#pragma unroll
  for (int i = 0; i < 2; ++i)
#pragma unroll
    for (int j = 0; j < 2; ++j) {
      const int nt = wid * 2 + j;
#pragma unroll
      for (int rg = 0; rg < 4; ++rg) {
        const int r = i * 16 + (lane >> 4) * 4 + rg;  // C/D: col=lane&15, row=quad*4+reg
        if (sm.ep.buck[r] == nt) sm.ep.yg[r][lane & 15] = acc[i][j][rg];
      }
    }
  __syncthreads();

  // tail network: 8 threads per row, 4 l2-neurons each, shuffle-reduce (width 8)
  {
    const int r = tid >> 3, q = tid & 7;
    const int b = sm.ep.buck[r];
    float act[30];
#pragma unroll
    for (int c = 0; c < 15; ++c) {
      const float v = sm.ep.yg[r][c] + sm.ep.bias[b * 16 + c];
      act[c]      = fminf(v * v * (127.0f / 128.0f), 1.0f);
      act[15 + c] = fminf(fmaxf(v, 0.0f), 1.0f);
    }
    const float y15 = sm.ep.yg[r][15] + sm.ep.bias[b * 16 + 15];  // l1c_out + l1f_out
    float o = 0.0f;
#pragma unroll
    for (int nn = 0; nn < 4; ++nn) {
      const int n = q * 4 + nn;
      float s = sm.ep.l2b[b * 32 + n];
#pragma unroll
      for (int k = 0; k < 30; ++k) s += act[k] * sm.ep.l2w[(n * 30 + k) * 9 + b];
      s = fminf(fmaxf(s, 0.0f), 1.0f);
      o += s * sm.ep.outw[n * 8 + b];
    }
    o += __shfl_down(o, 4, 8);
    o += __shfl_down(o, 2, 8);
    o += __shfl_down(o, 1, 8);
    if (q == 0) out[rowbase + r] = o + y15 + goutb[b];
  }
}

extern "C" void kernel_launch(void* const* d_in, const int* in_sizes, int n_in,
                              void* d_out, int out_size, void* d_ws, size_t ws_size,
                              hipStream_t stream) {
  const float* x    = (const float*)d_in[0];
  const int*   lsi  = (const int*)d_in[1];
  const float* l1w  = (const float*)d_in[2];
  const float* l1b  = (const float*)d_in[3];
  const float* l1fw = (const float*)d_in[4];
  const float* l1fb = (const float*)d_in[5];
  const float* l2w  = (const float*)d_in[6];
  const float* l2b  = (const float*)d_in[7];
  const float* outw = (const float*)d_in[8];
  const float* outb = (const float*)d_in[9];
  float* out = (float*)d_out;

  unsigned short* cw = (unsigned short*)d_ws;                    // 128*3072 bf16 = 786432 B (fragment order)
  float* cb = (float*)((char*)d_ws + 128 * L1D * sizeof(unsigned short)); // +512 B

  prep_kernel<<<dim3(12, 128), 256, 0, stream>>>(l1w, l1b, l1fw, l1fb, cw, cb);
  fused_kernel<<<NB / BM, 256, 0, stream>>>(x, lsi, cw, cb, l2w, l2b, outw, outb, out);
}